// Round 2
// baseline (124.195 us; speedup 1.0000x reference)
//
#include <hip/hip_runtime.h>

// Paillier sum-pooling = windowed modular product of ciphertexts mod n^2.
// N = 46337, NSQ = N*N = 2147117569 < 2^31  -> inputs arrive as int32,
// products of two residues fit in uint64. Output dtype is integer ->
// harness reads d_out back as int32 (values < 2^31, exact).

#define NSQ 2147117569ULL

typedef int int4v __attribute__((ext_vector_type(4)));

__global__ __launch_bounds__(256) void paillier_pool_kernel(
    const int* __restrict__ x, int* __restrict__ out, int nwork)
{
    int wi = blockIdx.x * blockDim.x + threadIdx.x;
    if (wi >= nwork) return;

    // Each work item produces 4 consecutive-in-c outputs.
    int flat = wi << 2;                 // output flat index ((b*128+ho)*128+wo)*64+c
    int c  = flat & 63;
    int wo = (flat >> 6) & 127;
    int ho = (flat >> 13) & 127;
    int b  = flat >> 20;

    // input flat index: ((b*256 + 2*ho)*256 + 2*wo)*64 + c
    // per-h row stride = 256*64 = 16384 elements, per-w stride = 64.
    long long base = ((((long long)(b << 8) + (ho << 1)) << 8) + (wo << 1)) * 64 + c;

    int4v v00 = *(const int4v*)(x + base);
    int4v v01 = *(const int4v*)(x + base + 64);
    int4v v10 = *(const int4v*)(x + base + 16384);
    int4v v11 = *(const int4v*)(x + base + 16384 + 64);

    int4v r;
#pragma unroll
    for (int k = 0; k < 4; ++k) {
        unsigned long long t0 = (unsigned long long)(unsigned)v00[k] * (unsigned)v01[k] % NSQ;
        unsigned long long t1 = (unsigned long long)(unsigned)v10[k] * (unsigned)v11[k] % NSQ;
        unsigned long long t  = (t0 * t1) % NSQ;
        r[k] = (int)(unsigned)t;
    }

    *(int4v*)(out + flat) = r;
}

extern "C" void kernel_launch(void* const* d_in, const int* in_sizes, int n_in,
                              void* d_out, int out_size, void* d_ws, size_t ws_size,
                              hipStream_t stream) {
    const int* x = (const int*)d_in[0];
    int* out = (int*)d_out;

    const int nwork = out_size / 4;            // 33554432 / 4 = 8388608
    const int block = 256;
    const int grid = (nwork + block - 1) / block;  // 32768 blocks

    paillier_pool_kernel<<<grid, block, 0, stream>>>(x, out, nwork);
}

// Round 3
// 117.741 us; speedup vs baseline: 1.0548x; 1.0548x over previous
//
#include <hip/hip_runtime.h>

// Paillier sum-pooling = windowed modular product of ciphertexts mod n^2.
// N = 46337, NSQ = N*N = 2147117569 < 2^31  -> inputs arrive as int32,
// products of two residues fit in uint64. Output dtype is integer ->
// harness reads d_out back as int32 (values < 2^31, exact).
//
// Memory-bound: 537 MB read + 134 MB write. Grid-stride with 2048 resident
// blocks (8/CU) keeps waves alive with loads in flight; nontemporal hints
// because every byte is touched exactly once (pure stream, > L3).

#define NSQ 2147117569ULL

typedef int int4v __attribute__((ext_vector_type(4)));

__global__ __launch_bounds__(256) void paillier_pool_kernel(
    const int* __restrict__ x, int* __restrict__ out, int nwork)
{
    const int stride = gridDim.x * blockDim.x;           // 524288
    for (int wi = blockIdx.x * blockDim.x + threadIdx.x; wi < nwork; wi += stride) {
        // Each work item produces 4 consecutive-in-c outputs.
        int flat = wi << 2;              // output flat index ((b*128+ho)*128+wo)*64+c
        int c  = flat & 63;
        int wo = (flat >> 6) & 127;
        int ho = (flat >> 13) & 127;
        int b  = flat >> 20;

        // input flat index: ((b*256 + 2*ho)*256 + 2*wo)*64 + c   (max < 2^27, fits int)
        int base = (((b << 8) + (ho << 1) << 8) + (wo << 1)) * 64 + c;

        int4v v00 = __builtin_nontemporal_load((const int4v*)(x + base));
        int4v v01 = __builtin_nontemporal_load((const int4v*)(x + base + 64));
        int4v v10 = __builtin_nontemporal_load((const int4v*)(x + base + 16384));
        int4v v11 = __builtin_nontemporal_load((const int4v*)(x + base + 16384 + 64));

        int4v r;
#pragma unroll
        for (int k = 0; k < 4; ++k) {
            unsigned long long t0 = (unsigned long long)(unsigned)v00[k] * (unsigned)v01[k] % NSQ;
            unsigned long long t1 = (unsigned long long)(unsigned)v10[k] * (unsigned)v11[k] % NSQ;
            unsigned long long t  = (t0 * t1) % NSQ;
            r[k] = (int)(unsigned)t;
        }

        __builtin_nontemporal_store(r, (int4v*)(out + flat));
    }
}

extern "C" void kernel_launch(void* const* d_in, const int* in_sizes, int n_in,
                              void* d_out, int out_size, void* d_ws, size_t ws_size,
                              hipStream_t stream) {
    const int* x = (const int*)d_in[0];
    int* out = (int*)d_out;

    const int nwork = out_size / 4;      // 33554432 / 4 = 8388608
    const int block = 256;
    const int grid  = 2048;              // 8 blocks/CU, grid-stride x16 iterations

    paillier_pool_kernel<<<grid, block, 0, stream>>>(x, out, nwork);
}